// Round 6
// baseline (252.415 us; speedup 1.0000x reference)
//
#include <hip/hip_runtime.h>

// EMA scan: out[:,0,:] = x[:,0,:]; out[:,t,:] = 0.1*x[:,t,:] + 0.9*out[:,t-1,:]
// x: (16, 4096, 512) fp32.
//
// Chunked-scan: recurrence forgets at 0.9^W; each chunk rebuilds its carry with
// a W=64 warm-up from zero (measured absmax 7.8e-3, threshold 7.6e-2).
// CONSTRAINT: L >= W so t0-W >= 0 for every chunk >= 1 (L=32 faulted OOB at R4).
//
// R5 post-mortem: BW flat ~2.5-2.9 TB/s across 2->8 waves/CU; VGPR=36 shows the
// compiler re-serialized the ping-pong buffer. New theory: a wave covered only
// half a 2KB row (64 lanes x 16B), so every wave's stream was 1KB requests on a
// 2KB stride -> DRAM pages opened twice, ~half efficiency (2.9 ~= 6.3/2).
// R6: each thread owns TWO float4 columns (lane, lane+64) -> one wave covers the
// full row; an 8-step batch is a dense contiguous 16KB burst per wave (loads and
// stores), plus 2 independent FMA chains / 16 independent loads per batch.

typedef float vf4 __attribute__((ext_vector_type(4)));

constexpr int B = 16;
constexpr int T = 4096;
constexpr int D = 512;
constexpr int DV = D / 4;      // 128 float4 per row
constexpr int L = 64;          // chunk length (must be >= W)
constexpr int C = T / L;       // 64 chunks
constexpr int W = 64;          // warm-up steps (0.9^64 ~ 1.2e-3)
constexpr int UNR = 8;         // t-steps per batch -> 16 loads (16KB/wave) in flight
constexpr int NB = L / UNR;    // 8 main batches

static_assert(L >= W, "warm-up must not cross below t=0 for chunk 1");

__global__ __launch_bounds__(256)
void ema_chunked_kernel(const vf4* __restrict__ X, vf4* __restrict__ O) {
    const int g     = blockIdx.x * 256 + threadIdx.x;
    const int lane  = g & 63;                // dvec0 = lane, dvec1 = lane + 64
    const int chunk = (g >> 6) & (C - 1);    // wave-uniform
    const int b     = g >> 12;               // 64 * C = 4096 = 1<<12

    const float a  = 0.1f;
    const float bb = 0.9f;

    const int base0 = b * (T * DV) + lane;   // first half-row column
    const int base1 = base0 + 64;            // second half-row column
    const int t0    = chunk * L;

    vf4 y0, y1;
    if (chunk == 0) {
        // y_init = x0: main-loop step at t=0 gives 0.1*x0 + 0.9*x0 = x0 exactly.
        y0 = X[base0];
        y1 = X[base1];
    } else {
        y0 = (vf4)(0.f);
        y1 = (vf4)(0.f);
        const vf4* xp = X + (t0 - W) * DV;
        for (int kb = 0; kb < W / UNR; ++kb) {
            vf4 v0[UNR], v1[UNR];
            #pragma unroll
            for (int j = 0; j < UNR; ++j) {
                const int t = kb * UNR + j;
                v0[j] = xp[base0 + t * DV];
                v1[j] = xp[base1 + t * DV];
            }
            #pragma unroll
            for (int j = 0; j < UNR; ++j) {
                y0 = bb * y0 + a * v0[j];
                y1 = bb * y1 + a * v1[j];
            }
        }
    }

    const vf4* xp = X + t0 * DV;
    vf4*       op = O + t0 * DV;
    #pragma unroll
    for (int kb = 0; kb < NB; ++kb) {
        vf4 v0[UNR], v1[UNR];
        #pragma unroll
        for (int j = 0; j < UNR; ++j) {
            const int t = kb * UNR + j;
            v0[j] = xp[base0 + t * DV];
            v1[j] = xp[base1 + t * DV];
        }
        #pragma unroll
        for (int j = 0; j < UNR; ++j) {
            const int t = kb * UNR + j;
            y0 = bb * y0 + a * v0[j];
            op[base0 + t * DV] = y0;
            y1 = bb * y1 + a * v1[j];
            op[base1 + t * DV] = y1;
        }
    }
}

extern "C" void kernel_launch(void* const* d_in, const int* in_sizes, int n_in,
                              void* d_out, int out_size, void* d_ws, size_t ws_size,
                              hipStream_t stream) {
    const vf4* X = (const vf4*)d_in[0];
    vf4*       O = (vf4*)d_out;

    const int total_threads = B * C * 64;    // 65536 (each thread: 2 columns)
    const int block = 256;
    const int grid  = total_threads / block; // 256 blocks -> 4 waves/CU
    ema_chunked_kernel<<<grid, block, 0, stream>>>(X, O);
}